// Round 6
// baseline (7548.566 us; speedup 1.0000x reference)
//
#include <hip/hip_runtime.h>
#include <hip/hip_bf16.h>
#include <math.h>

// Problem dims
#define BB 64
#define TT 128
#define T1 127
#define OBS 512
#define HH 1024
#define LL 32
#define CC 32
#define AA 18
#define KIN 1042   // LC + A
#define G3 3072    // 3*H
#define NWG 256

__device__ __forceinline__ float4 ld4(const float* p) { return *(const float4*)p; }
__device__ __forceinline__ float2 lds2(const float* p) { return *(const float2*)p; }

// ---------------- transpose wih (3072 x 1042) -> wihT (1042 x 3072) ----------------
__global__ __launch_bounds__(256) void tr_k(const float* __restrict__ wih, float* __restrict__ wihT)
{
    __shared__ float tile[32][33];
    int g0 = blockIdx.x * 32;
    int k0 = blockIdx.y * 32;
    int tx = threadIdx.x, ty = threadIdx.y;
    #pragma unroll
    for (int r = 0; r < 32; r += 8) {
        int g = g0 + ty + r, k = k0 + tx;
        tile[ty + r][tx] = (k < KIN) ? wih[(size_t)g * KIN + k] : 0.f;
    }
    __syncthreads();
    #pragma unroll
    for (int r = 0; r < 32; r += 8) {
        int k = k0 + ty + r, g = g0 + tx;
        if (k < KIN) wihT[(size_t)k * G3 + g] = tile[tx][ty + r];
    }
}

// ---------------- transpose postw top half (1024 x 1024) -> postwT (n-major) --------
__global__ __launch_bounds__(256) void tr2_k(const float* __restrict__ src, float* __restrict__ dst)
{
    __shared__ float tile[32][33];
    int r0 = blockIdx.x * 32;
    int c0 = blockIdx.y * 32;
    int tx = threadIdx.x, ty = threadIdx.y;
    #pragma unroll
    for (int rr = 0; rr < 32; rr += 8)
        tile[ty + rr][tx] = src[(size_t)(r0 + ty + rr) * HH + c0 + tx];
    __syncthreads();
    #pragma unroll
    for (int rr = 0; rr < 32; rr += 8)
        dst[(size_t)(c0 + ty + rr) * HH + r0 + tx] = tile[tx][ty + rr];
}

// ---------------- fp32 GEMM: C = A(MxK) @ B(KxN) + bias (+extra) (relu) --------------
template<int RELU, int HAS_EXTRA, int AAL>
__global__ __launch_bounds__(256) void gemm_k(const float* __restrict__ A, const float* __restrict__ Bm,
    float* __restrict__ Cm, int M, int N, int K,
    const float* __restrict__ bias, const float* __restrict__ extra)
{
    __shared__ float As[16][132];
    __shared__ float Bs[16][132];
    int tid = threadIdx.x;
    int tx = tid & 15, ty = tid >> 4;
    int m0 = blockIdx.y * 128, n0 = blockIdx.x * 128;
    float acc[8][8];
    #pragma unroll
    for (int i = 0; i < 8; ++i)
        #pragma unroll
        for (int j = 0; j < 8; ++j) acc[i][j] = 0.f;

    int arow = tid >> 1;
    int ak0  = (tid & 1) * 8;
    int am   = m0 + arow;

    float  ar[8];
    float4 br[2];

    auto loadA = [&](int kt) {
        if (am < M) {
            const float* ap = A + (size_t)am * K + kt + ak0;
            if (AAL) {
                float4 v0 = ld4(ap), v1 = ld4(ap + 4);
                ar[0] = v0.x; ar[1] = v0.y; ar[2] = v0.z; ar[3] = v0.w;
                ar[4] = v1.x; ar[5] = v1.y; ar[6] = v1.z; ar[7] = v1.w;
            } else {
                #pragma unroll
                for (int e = 0; e < 8; ++e) ar[e] = ap[e];
            }
        } else {
            #pragma unroll
            for (int e = 0; e < 8; ++e) ar[e] = 0.f;
        }
    };
    auto loadB = [&](int kt) {
        #pragma unroll
        for (int i2 = 0; i2 < 2; ++i2) {
            int idx = tid * 2 + i2;
            int kk = idx >> 5, c4 = idx & 31;
            br[i2] = ld4(Bm + (size_t)(kt + kk) * N + n0 + c4 * 4);
        }
    };

    loadA(0); loadB(0);

    for (int kt = 0; kt < K; kt += 16) {
        #pragma unroll
        for (int e = 0; e < 8; ++e) As[ak0 + e][arow] = ar[e];
        #pragma unroll
        for (int i2 = 0; i2 < 2; ++i2) {
            int idx = tid * 2 + i2;
            int kk = idx >> 5, c4 = idx & 31;
            *(float4*)&Bs[kk][c4 * 4] = br[i2];
        }
        __syncthreads();
        if (kt + 16 < K) { loadA(kt + 16); loadB(kt + 16); }
        #pragma unroll
        for (int k = 0; k < 16; ++k) {
            float av[8], bv[8];
            *(float4*)&av[0] = *(const float4*)&As[k][ty * 8];
            *(float4*)&av[4] = *(const float4*)&As[k][ty * 8 + 4];
            *(float4*)&bv[0] = *(const float4*)&Bs[k][tx * 8];
            *(float4*)&bv[4] = *(const float4*)&Bs[k][tx * 8 + 4];
            #pragma unroll
            for (int i = 0; i < 8; ++i)
                #pragma unroll
                for (int j = 0; j < 8; ++j)
                    acc[i][j] = fmaf(av[i], bv[j], acc[i][j]);
        }
        __syncthreads();
    }
    #pragma unroll
    for (int i = 0; i < 8; ++i) {
        int m = m0 + ty * 8 + i;
        if (m >= M) break;
        #pragma unroll
        for (int jh = 0; jh < 2; ++jh) {
            int n = n0 + tx * 8 + jh * 4;
            float4 v;
            v.x = acc[i][jh * 4 + 0] + bias[n + 0];
            v.y = acc[i][jh * 4 + 1] + bias[n + 1];
            v.z = acc[i][jh * 4 + 2] + bias[n + 2];
            v.w = acc[i][jh * 4 + 3] + bias[n + 3];
            if (HAS_EXTRA) {
                float4 e = ld4(extra + (size_t)m * N + n);
                v.x += e.x; v.y += e.y; v.z += e.z; v.w += e.w;
            }
            if (RELU) {
                v.x = fmaxf(v.x, 0.f); v.y = fmaxf(v.y, 0.f);
                v.z = fmaxf(v.z, 0.f); v.w = fmaxf(v.w, 0.f);
            }
            *(float4*)(Cm + (size_t)m * N + n) = v;
        }
    }
}

// ---------------- step-0 sampling: argmax(epost[:,0] + gumbel[0]) ----------------
__global__ __launch_bounds__(256) void samp0_k(const float* __restrict__ epost, const float* __restrict__ gumbel,
                                               float* __restrict__ samples_out, int* __restrict__ sidx)
{
    int b = blockIdx.x;
    int tid = threadIdx.x;
    int l = tid >> 3, s = tid & 7;
    const float* lg = epost + ((size_t)b * TT + 0) * HH + l * 32;
    const float* gm = gumbel + (((size_t)0 * BB + b) * LL + l) * CC;
    float u[4];
    #pragma unroll
    for (int i = 0; i < 4; ++i) { int c = s * 4 + i; u[i] = lg[c] + gm[c]; }
    float best = u[0]; int bi = s * 4;
    #pragma unroll
    for (int i = 1; i < 4; ++i) { if (u[i] > best) { best = u[i]; bi = s * 4 + i; } }
    for (int m = 1; m < 8; m <<= 1) {
        float ov = __shfl_xor(best, m, 8);
        int   oi = __shfl_xor(bi, m, 8);
        if (ov > best || (ov == best && oi < bi)) { best = ov; bi = oi; }
    }
    float* so = samples_out + ((size_t)b * T1 + 0) * HH + l * 32;
    #pragma unroll
    for (int i = 0; i < 4; ++i) { int c = s * 4 + i; so[c] = (c == bi) ? 1.f : 0.f; }
    if (s == 0) sidx[((size_t)0 * BB + b) * LL + l] = bi;
}

// ---------------- split flag barrier: zero cache-maintenance ops ----------------
__device__ __forceinline__ void bar_arrive(unsigned int* __restrict__ f, int bid)
{
    __syncthreads();   // per-wave vmcnt(0) drain before s_barrier -> prior stores @MALL
    if (threadIdx.x == 0)
        __hip_atomic_store(&f[bid], 1u, __ATOMIC_RELAXED, __HIP_MEMORY_SCOPE_AGENT);
}
__device__ __forceinline__ void bar_wait(unsigned int* __restrict__ f, int bid)
{
    int tid = threadIdx.x;
    if (tid < 64) {
        int it = 0;
        for (;;) {
            unsigned int v0 = __hip_atomic_load(&f[tid],       __ATOMIC_RELAXED, __HIP_MEMORY_SCOPE_AGENT);
            unsigned int v1 = __hip_atomic_load(&f[64 + tid],  __ATOMIC_RELAXED, __HIP_MEMORY_SCOPE_AGENT);
            unsigned int v2 = __hip_atomic_load(&f[128 + tid], __ATOMIC_RELAXED, __HIP_MEMORY_SCOPE_AGENT);
            unsigned int v3 = __hip_atomic_load(&f[192 + tid], __ATOMIC_RELAXED, __HIP_MEMORY_SCOPE_AGENT);
            if (__all((v0 & v1 & v2 & v3) != 0)) break;
            __builtin_amdgcn_s_sleep(4);
            if (((++it) & 2047) == 2047 && tid == 0) {   // insurance escalation
                __hip_atomic_store(&f[bid], 1u, __ATOMIC_RELEASE, __HIP_MEMORY_SCOPE_AGENT);
                (void)__hip_atomic_load(&f[bid], __ATOMIC_ACQUIRE, __HIP_MEMORY_SCOPE_AGENT);
            }
        }
    }
    __syncthreads();
}

// ---------------- persistent scan kernel (register-microtiled, 1 hard barrier/step) --
// 256 blocks x 512 threads, 1 block/CU. LDS layout (dwords):
#define WF_BASE 0            // wfull  [12][8][136]  = 13056  (whh slice, persists)
#define R1_BASE 13056        // h_sA [64][136] | h_sB [8][1088] = 8704
#define R2_BASE 21760        // psA [4][64][33] | psB [8][32][33] = 8448
#define OFF_BASE 30208       // off_s [64][33] ints = 2112
#define GATH_BASE 32320      // gath [3][64][4] = 768
#define SM_TOT 33088         // 132,352 B
__global__ __launch_bounds__(512) void scan_k(
    float* __restrict__ hseq, float* __restrict__ hso,
    const float* __restrict__ wihT, const float* __restrict__ whh,
    const float* __restrict__ bih, const float* __restrict__ bhh,
    int* __restrict__ sidx, const int* __restrict__ act,
    const float* __restrict__ postwT, const float* __restrict__ epost,
    const float* __restrict__ gum, float* __restrict__ plog,
    float* __restrict__ smo, unsigned int* __restrict__ flags)
{
    __shared__ float sm[SM_TOT];
    int* off_s = (int*)&sm[OFF_BASE];

    const int tid = threadIdx.x;
    const int bid = blockIdx.x;
    // phase A ids: block owns gate-cols j0..j0+3 (x3 gates), all 64 batches
    const int sb = (bid & 7) * 32 + (bid >> 3);
    const int j0 = sb * 4;
    const int bposA = tid >> 6;          // 0..7  (8-batch group)
    const int cposA = (tid >> 5) & 1;    // 0..1  (j-pair)
    const int ksA   = tid & 31;          // K-split
    const int swzA  = ksA * 4 + 2 * (ksA >> 3);   // 8B-granular bank swizzle
    // phase B ids: block owns (8-batch chunk b0, latent l)
    const int l  = bid & 31;
    const int bc = bid >> 5;
    const int b0 = bc * 8;
    const int cposB = tid >> 5;          // 0..15 (c-pair)
    const int ksB   = tid & 31;          // K-split
    const int n0 = l * 32;

    // ---- stage whh slice into wfull once (rows r = g*4+q -> col g*1024+j0+q) ----
    for (int idx = tid; idx < 3072; idx += 512) {
        int r = idx >> 8;                // 0..11
        int rem = idx & 255;
        int kc = rem >> 5, ks = rem & 31;
        int g = r >> 2, q = r & 3;
        float4 v = ld4(whh + (size_t)(g * 1024 + j0 + q) * HH + kc * 128 + ks * 4);
        int ph = WF_BASE + r * 1088 + kc * 136 + ks * 4 + 2 * (ks >> 3) + ((r >> 1) & 1) * 2;
        *(float2*)&sm[ph]     = make_float2(v.x, v.y);
        *(float2*)&sm[ph + 2] = make_float2(v.z, v.w);
    }
    __syncthreads();

    for (int t = 1; t <= 127; ++t) {
        const float* hprev = hseq + (size_t)(t - 1) * 65536;

        // ============ A-dots: acc[jj][g][bb] over this thread's 32 K-comb ============
        float acc[2][3][8];
        #pragma unroll
        for (int jj = 0; jj < 2; ++jj)
            #pragma unroll
            for (int g = 0; g < 3; ++g)
                #pragma unroll
                for (int bb = 0; bb < 8; ++bb) acc[jj][g][bb] = 0.f;

        const int rowbase = bposA * 8 + cposA * 4;
        float4 pre[4];
        #pragma unroll
        for (int i = 0; i < 4; ++i)
            pre[i] = ld4(hprev + (rowbase + i) * HH + ksA * 4);

        for (int kc = 0; kc < 8; ++kc) {
            __syncthreads();
            #pragma unroll
            for (int i = 0; i < 4; ++i) {
                int row = rowbase + i;
                int ph = R1_BASE + row * 136 + swzA + ((row >> 2) & 1) * 2;
                *(float2*)&sm[ph]     = make_float2(pre[i].x, pre[i].y);
                *(float2*)&sm[ph + 2] = make_float2(pre[i].z, pre[i].w);
            }
            __syncthreads();
            if (kc < 7) {
                #pragma unroll
                for (int i = 0; i < 4; ++i)
                    pre[i] = ld4(hprev + (rowbase + i) * HH + (kc + 1) * 128 + ksA * 4);
            }
            float2 h0[8], h1[8];
            #pragma unroll
            for (int bb = 0; bb < 8; ++bb) {
                int row = bposA * 8 + bb;
                int ph = R1_BASE + row * 136 + swzA + ((row >> 2) & 1) * 2;
                h0[bb] = lds2(&sm[ph]); h1[bb] = lds2(&sm[ph + 2]);
            }
            #pragma unroll
            for (int jj = 0; jj < 2; ++jj)
                #pragma unroll
                for (int g = 0; g < 3; ++g) {
                    int r = g * 4 + cposA * 2 + jj;
                    int ph = WF_BASE + r * 1088 + kc * 136 + swzA + ((r >> 1) & 1) * 2;
                    float2 w0 = lds2(&sm[ph]), w1 = lds2(&sm[ph + 2]);
                    #pragma unroll
                    for (int bb = 0; bb < 8; ++bb)
                        acc[jj][g][bb] += h0[bb].x * w0.x + h0[bb].y * w0.y
                                        + h1[bb].x * w1.x + h1[bb].y * w1.y;
                }
        }

        // ============ wait sidx_{t-1} (soft: hidden behind the dots above) ============
        if (t > 1) bar_wait(flags + (size_t)(127 + t - 2) * NWG, bid);
        #pragma unroll
        for (int u = 0; u < 4; ++u) {
            int i = tid + u * 512;      // 0..2047
            int b = i >> 5, l2 = i & 31;
            off_s[b * 33 + l2] = l2 * 32 + sidx[(size_t)(t - 1) * 2048 + b * 32 + l2];
        }
        if (tid < 64) off_s[tid * 33 + 32] = 1024 + act[tid * TT + (t - 1)];
        __syncthreads();

        // gather one-hot rows of wihT (tid<192: g = tid>>6, b = tid&63), f4 over 4 j
        if (tid < 192) {
            int g = tid >> 6, b = tid & 63;
            float4 gv = make_float4(0.f, 0.f, 0.f, 0.f);
            #pragma unroll 4
            for (int i = 0; i < 33; ++i) {
                int o = off_s[b * 33 + i];
                float4 v = ld4(wihT + (size_t)o * G3 + g * 1024 + j0);
                gv.x += v.x; gv.y += v.y; gv.z += v.z; gv.w += v.w;
            }
            *(float4*)&sm[GATH_BASE + (g * 64 + b) * 4] = gv;
        }
        int jo = 0, bo = 0; float hp = 0.f;
        if (tid < 256) { jo = tid >> 6; bo = tid & 63; hp = hprev[bo * HH + j0 + jo]; }

        // ============ reduce A over 32 K-splits (per gate, psA reused) ============
        float gsum0 = 0.f, gsum1 = 0.f, gsum2 = 0.f;
        #pragma unroll
        for (int g = 0; g < 3; ++g) {
            __syncthreads();
            #pragma unroll
            for (int jj = 0; jj < 2; ++jj)
                #pragma unroll
                for (int bb = 0; bb < 8; ++bb)
                    sm[R2_BASE + ((cposA * 2 + jj) * 64 + bposA * 8 + bb) * 33 + ksA] = acc[jj][g][bb];
            __syncthreads();
            if (tid < 256) {
                float s = 0.f;
                #pragma unroll
                for (int k = 0; k < 32; ++k) s += sm[R2_BASE + (jo * 64 + bo) * 33 + k];
                if (g == 0) gsum0 = s; else if (g == 1) gsum1 = s; else gsum2 = s;
            }
        }

        // ============ combine + publish h_t ============
        if (tid < 256) {
            int col = j0 + jo;
            float gr = sm[GATH_BASE + (0 * 64 + bo) * 4 + jo];
            float gz = sm[GATH_BASE + (1 * 64 + bo) * 4 + jo];
            float gn = sm[GATH_BASE + (2 * 64 + bo) * 4 + jo];
            float rr = 1.f / (1.f + expf(-(gr + bih[col] + gsum0 + bhh[col])));
            float zz = 1.f / (1.f + expf(-(gz + bih[1024 + col] + gsum1 + bhh[1024 + col])));
            float nn = tanhf(gn + bih[2048 + col] + rr * (gsum2 + bhh[2048 + col]));
            float hv = (1.f - zz) * nn + zz * hp;
            __hip_atomic_store(&hseq[(size_t)t * 65536 + bo * HH + col], hv,
                               __ATOMIC_RELAXED, __HIP_MEMORY_SCOPE_AGENT);
            hso[((size_t)bo * T1 + (t - 1)) * HH + col] = hv;
        }
        bar_arrive(flags + (size_t)(t - 1) * NWG, bid);   // hard barrier: h_t broadcast
        bar_wait(flags + (size_t)(t - 1) * NWG, bid);

        // ============ B: logits_t = h_t @ postwT + epost; sample ============
        const float* hcur = hseq + (size_t)t * 65536;
        {
            int b = cposB >> 1, ithalf = cposB & 1;
            float4 v[4];
            #pragma unroll
            for (int e = 0; e < 4; ++e)
                v[e] = ld4(hcur + (b0 + b) * HH + ksB * 32 + ithalf * 16 + e * 4);
            __syncthreads();
            #pragma unroll
            for (int e = 0; e < 4; ++e) {
                int it = ithalf * 4 + e;
                int ph = R1_BASE + b * 1088 + ksB * 34 + it * 4 + ((it >> 2) & 1) * 2;
                *(float2*)&sm[ph]     = make_float2(v[e].x, v[e].y);
                *(float2*)&sm[ph + 2] = make_float2(v[e].z, v[e].w);
            }
            __syncthreads();
        }
        float accB[2][8];
        #pragma unroll
        for (int cc = 0; cc < 2; ++cc)
            #pragma unroll
            for (int b = 0; b < 8; ++b) accB[cc][b] = 0.f;
        #pragma unroll
        for (int it = 0; it < 8; ++it) {
            float4 wv0 = ld4(postwT + (size_t)(n0 + cposB * 2 + 0) * HH + ksB * 32 + it * 4);
            float4 wv1 = ld4(postwT + (size_t)(n0 + cposB * 2 + 1) * HH + ksB * 32 + it * 4);
            #pragma unroll
            for (int b = 0; b < 8; ++b) {
                int ph = R1_BASE + b * 1088 + ksB * 34 + it * 4 + ((it >> 2) & 1) * 2;
                float2 a0 = lds2(&sm[ph]), a1 = lds2(&sm[ph + 2]);
                accB[0][b] += a0.x * wv0.x + a0.y * wv0.y + a1.x * wv0.z + a1.y * wv0.w;
                accB[1][b] += a0.x * wv1.x + a0.y * wv1.y + a1.x * wv1.z + a1.y * wv1.w;
            }
        }
        __syncthreads();
        #pragma unroll
        for (int cc = 0; cc < 2; ++cc)
            #pragma unroll
            for (int b = 0; b < 8; ++b)
                sm[R2_BASE + (b * 32 + ksB) * 33 + cposB * 2 + cc] = accB[cc][b];
        __syncthreads();
        if (tid < 256) {
            int b = tid >> 5, c = tid & 31;
            float s = 0.f;
            #pragma unroll
            for (int k = 0; k < 32; ++k) s += sm[R2_BASE + (b * 32 + k) * 33 + c];
            int bg = b0 + b, n = n0 + c;
            float lg = s + epost[((size_t)bg * TT + t) * HH + n];
            plog[((size_t)(t - 1) * BB + bg) * HH + n] = lg;
            if (t <= 126) {
                float u = lg + gum[(((size_t)t * BB + bg) * LL + l) * CC + c];
                float best = u; int bi = c;
                for (int m = 1; m < 32; m <<= 1) {
                    float ov = __shfl_xor(best, m, 32);
                    int   oi = __shfl_xor(bi, m, 32);
                    if (ov > best || (ov == best && oi < bi)) { best = ov; bi = oi; }
                }
                smo[((size_t)bg * T1 + t) * HH + n] = (c == bi) ? 1.f : 0.f;
                if (c == 0)
                    __hip_atomic_store(&sidx[((size_t)t * BB + bg) * LL + l], bi,
                                       __ATOMIC_RELAXED, __HIP_MEMORY_SCOPE_AGENT);
            }
        }
        if (t <= 126) bar_arrive(flags + (size_t)(127 + t - 1) * NWG, bid);  // soft: waited next iter
    }
}

// ---------------- KL reduction ----------------
__global__ __launch_bounds__(256) void kl_k(const float* __restrict__ prior,
    const float* __restrict__ plog, float* __restrict__ out)
{
    int rrow = blockIdx.x;
    int b = rrow / T1, i = rrow - b * T1;
    int tid = threadIdx.x;
    int l = tid >> 3, s = tid & 7;
    const float* pp = prior + (size_t)rrow * HH + l * 32;
    const float* qq = plog + ((size_t)i * BB + b) * HH + l * 32;
    float pv[4], qv[4];
    #pragma unroll
    for (int e = 0; e < 4; ++e) { int c = s * 4 + e; pv[e] = pp[c]; qv[e] = qq[c]; }
    float mp = fmaxf(fmaxf(pv[0], pv[1]), fmaxf(pv[2], pv[3]));
    float mq = fmaxf(fmaxf(qv[0], qv[1]), fmaxf(qv[2], qv[3]));
    for (int m = 1; m < 8; m <<= 1) {
        mp = fmaxf(mp, __shfl_xor(mp, m, 8));
        mq = fmaxf(mq, __shfl_xor(mq, m, 8));
    }
    float sp = 0.f, sq = 0.f;
    #pragma unroll
    for (int e = 0; e < 4; ++e) { sp += expf(pv[e] - mp); sq += expf(qv[e] - mq); }
    for (int m = 1; m < 8; m <<= 1) { sp += __shfl_xor(sp, m, 8); sq += __shfl_xor(sq, m, 8); }
    float lsp = mp + logf(sp), lsq = mq + logf(sq);
    float kf = 0.f, kr = 0.f;
    #pragma unroll
    for (int e = 0; e < 4; ++e) {
        float lp = pv[e] - lsp, lq = qv[e] - lsq;
        float eq = expf(lq), ep = expf(lp);
        kf += eq * (lq - lp); kr += ep * (lp - lq);
    }
    for (int m = 1; m < 8; m <<= 1) { kf += __shfl_xor(kf, m, 8); kr += __shfl_xor(kr, m, 8); }
    __shared__ float kfs[32], krs[32];
    if (s == 0) { kfs[l] = kf; krs[l] = kr; }
    __syncthreads();
    if (tid == 0) {
        float f = 0.f, r = 0.f;
        for (int l2 = 0; l2 < 32; ++l2) { f += kfs[l2]; r += krs[l2]; }
        float val = fmaxf(0.8f * f + 0.2f * r, 1.0f);
        atomicAdd(out, val * (1.0f / 8128.0f));
    }
}

// ---------------- gather-sum of dec_w1 bottom rows per (b,i) ----------------
__global__ __launch_bounds__(256) void gsum_k(const float* __restrict__ dw1bot,
    const int* __restrict__ sidx, float* __restrict__ gsum)
{
    int rrow = blockIdx.x;
    int b = rrow / T1, i = rrow - b * T1;
    __shared__ int offs[32];
    int tid = threadIdx.x;
    if (tid < 32) offs[tid] = tid * 32 + sidx[((size_t)i * BB + b) * LL + tid];
    __syncthreads();
    int n = tid * 4;
    float4 acc = make_float4(0.f, 0.f, 0.f, 0.f);
    #pragma unroll 4
    for (int l = 0; l < 32; ++l) {
        float4 v = ld4(dw1bot + (size_t)offs[l] * HH + n);
        acc.x += v.x; acc.y += v.y; acc.z += v.z; acc.w += v.w;
    }
    *(float4*)(gsum + (size_t)rrow * HH + n) = acc;
}

// ---------------- reward head ----------------
__global__ __launch_bounds__(256) void rew_k(const float* __restrict__ hs, const float* __restrict__ reww,
    const float* __restrict__ rewb, const int* __restrict__ sidx, float* __restrict__ pred)
{
    int rrow = blockIdx.x * 4 + (threadIdx.x >> 6);
    int lane = threadIdx.x & 63;
    int b = rrow / T1, i = rrow - b * T1;
    const float* hp = hs + (size_t)rrow * HH;
    float acc = 0.f;
    for (int k = lane; k < HH; k += 64) acc += hp[k] * reww[k];
    for (int m = 1; m < 64; m <<= 1) acc += __shfl_xor(acc, m, 64);
    if (lane == 0) {
        float g = 0.f;
        const int* sp = sidx + ((size_t)i * BB + b) * LL;
        for (int l = 0; l < 32; ++l) g += reww[1024 + l * 32 + sp[l]];
        pred[rrow] = acc + g + rewb[0];
    }
}

extern "C" void kernel_launch(void* const* d_in, const int* in_sizes, int n_in,
                              void* d_out, int out_size, void* d_ws, size_t ws_size,
                              hipStream_t stream) {
    const float* obs   = (const float*)d_in[0];
    const float* gum   = (const float*)d_in[1];
    const float* ew1   = (const float*)d_in[2];
    const float* eb1   = (const float*)d_in[3];
    const float* ew2   = (const float*)d_in[4];
    const float* eb2   = (const float*)d_in[5];
    const float* wih   = (const float*)d_in[6];
    const float* whh   = (const float*)d_in[7];
    const float* bih   = (const float*)d_in[8];
    const float* bhh   = (const float*)d_in[9];
    const float* priw  = (const float*)d_in[10];
    const float* prib  = (const float*)d_in[11];
    const float* postw = (const float*)d_in[12];
    const float* postb = (const float*)d_in[13];
    const float* dw1   = (const float*)d_in[14];
    const float* db1   = (const float*)d_in[15];
    const float* dw2   = (const float*)d_in[16];
    const float* db2   = (const float*)d_in[17];
    const float* reww  = (const float*)d_in[18];
    const float* rewb  = (const float*)d_in[19];
    const int*   act   = (const int*)d_in[20];
    (void)in_sizes; (void)n_in; (void)out_size; (void)ws_size;

    float* ws = (float*)d_ws;
    float* wihT   = ws;                        // 1042*3072 = 3,201,024
    float* postwT = wihT + 3201024;            // 1024*1024 = 1,048,576
    float* bufA   = postwT + 1048576;          // 8192*1024 : e1 -> epost -> prior_logits
    float* bufB   = bufA + 8388608;            // 8192*1024 : e -> hseq[128][64][1024] -> dec_tmp
    float* plog   = bufB + 8388608;            // 127*64*1024 : post_logits -> gsum
    int*   sidx   = (int*)(plog + 8323072);    // 127*64*32 ints = 260,096
    unsigned int* flags = (unsigned int*)(sidx + 260096);  // 253*256 barrier flags

    float* out = (float*)d_out;
    float* recon = out;                     // 8128*512
    float* pred  = out + 4161536;           // 8128
    float* klo   = pred + 8128;             // 1
    float* hso   = klo + 1;                 // 8128*1024 (NOT 16B-aligned: scalar/AAL=0 paths only)
    float* smo   = hso + 8323072;           // 8128*1024

    hipMemsetAsync(klo, 0, sizeof(float), stream);
    hipMemsetAsync(flags, 0, 253 * 256 * sizeof(unsigned int), stream);

    tr_k<<<dim3(96, 33), dim3(32, 8), 0, stream>>>(wih, wihT);
    tr2_k<<<dim3(32, 32), dim3(32, 8), 0, stream>>>(postw, postwT);
    // encoder
    gemm_k<1,0,1><<<dim3(8, 64), 256, 0, stream>>>(obs,  ew1, bufA, 8192, 1024, 512,  eb1, nullptr);
    gemm_k<1,0,1><<<dim3(8, 64), 256, 0, stream>>>(bufA, ew2, bufB, 8192, 1024, 1024, eb2, nullptr);
    // epost = e @ post_w[1024:] + post_b  (hoisted e-half of posterior logits)
    gemm_k<0,0,1><<<dim3(8, 64), 256, 0, stream>>>(bufB, postw + 1024 * 1024, bufA, 8192, 1024, 1024, postb, nullptr);
    // step-0 sample
    samp0_k<<<64, 256, 0, stream>>>(bufA, gum, smo, sidx);

    // hseq[0] = h0 = zeros (bufB's e-content no longer needed)
    hipMemsetAsync(bufB, 0, 65536 * sizeof(float), stream);

    // persistent scan (127 steps; 1 hard + 1 hidden barrier per step)
    {
        float* hseq_p = bufB; float* hso_p = hso;
        const float* wihT_p = wihT; const float* whh_p = whh;
        const float* bih_p = bih; const float* bhh_p = bhh;
        int* sidx_p = sidx; const int* act_p = act;
        const float* postwT_p = postwT; const float* epost_p = bufA;
        const float* gum_p = gum; float* plog_p = plog; float* smo_p = smo;
        unsigned int* flags_p = flags;
        void* args[] = { &hseq_p, &hso_p, &wihT_p, &whh_p, &bih_p, &bhh_p,
                         &sidx_p, &act_p, &postwT_p, &epost_p, &gum_p, &plog_p, &smo_p, &flags_p };
        hipLaunchCooperativeKernel((const void*)scan_k, dim3(256), dim3(512), args, 0, stream);
    }

    // prior logits (A=hso is not 16B-aligned -> AAL=0)
    gemm_k<0,0,0><<<dim3(8, 64), 256, 0, stream>>>(hso, priw, bufA, 8128, 1024, 1024, prib, nullptr);
    // KL
    kl_k<<<8128, 256, 0, stream>>>(bufA, plog, klo);
    // decoder: gather-sum then 2 GEMMs (bufB reused as dec_tmp; hseq dead)
    gsum_k<<<8128, 256, 0, stream>>>(dw1 + 1024 * 1024, sidx, plog);
    gemm_k<1,1,0><<<dim3(8, 64), 256, 0, stream>>>(hso, dw1, bufB, 8128, 1024, 1024, db1, plog);
    gemm_k<0,0,1><<<dim3(4, 64), 256, 0, stream>>>(bufB, dw2, recon, 8128, 512, 1024, db2, nullptr);
    // reward
    rew_k<<<2032, 256, 0, stream>>>(hso, reww, rewb, sidx, pred);
}